// Round 13
// baseline (1945.153 us; speedup 1.0000x reference)
//
#include <hip/hip_runtime.h>
#include <cstdint>
#include <cmath>

#define D_MODEL 1024
#define T_SEQ   1024
#define NHEAD   16
#define NLAYER  8
#define HID     2734
#define HID_PAD 2816
#define NTOK    2048
#define VOCAB   32000

typedef __bf16 bf16x8 __attribute__((ext_vector_type(8)));
typedef __bf16 bf16x4 __attribute__((ext_vector_type(4)));
typedef float  f32x4  __attribute__((ext_vector_type(4)));

__device__ inline bf16x4 to_bf4(float a, float b, float c, float d) {
  bf16x4 t; t[0] = (__bf16)a; t[1] = (__bf16)b; t[2] = (__bf16)c; t[3] = (__bf16)d; return t;
}

__device__ inline void gload16(const __bf16* g, __bf16* l) {
  __builtin_amdgcn_global_load_lds(
      (const __attribute__((address_space(1))) void*)g,
      (__attribute__((address_space(3))) void*)l, 16, 0, 0);
}

// ---------------------------------------------------------------------------
// Embedding gather + RoPE cos/sin table, one launch.
// ---------------------------------------------------------------------------
__global__ __launch_bounds__(256) void embed_rope_kernel(const int* __restrict__ idx,
                                                         const float* __restrict__ W,
                                                         float* __restrict__ x,
                                                         float* __restrict__ tab) {
  int blk = blockIdx.x;
  if (blk < NTOK) {
    int v = idx[blk];
    float4 val = *(const float4*)&W[(size_t)v * D_MODEL + threadIdx.x * 4];
    *(float4*)&x[(size_t)blk * D_MODEL + threadIdx.x * 4] = val;
  } else {
    int p = (blk - NTOK) * 256 + threadIdx.x;
    int t = p >> 5, i = p & 31;
    float freq = exp2f(-(float)i * (13.287712379549449f / 32.0f));
    float sn, cs;
    sincosf((float)t * freq, &sn, &cs);
    tab[p] = cs;
    tab[32768 + p] = sn;
  }
}

// ---------------------------------------------------------------------------
// RMSNorm: f32 in -> bf16 out
// ---------------------------------------------------------------------------
__global__ __launch_bounds__(256) void rmsnorm_kernel(const float* __restrict__ x,
                                                      const float* __restrict__ w,
                                                      __bf16* __restrict__ out) {
  int row = blockIdx.x;
  int tid = threadIdx.x;
  float4 v = *(const float4*)&x[(size_t)row * D_MODEL + tid * 4];
  float s = v.x * v.x + v.y * v.y + v.z * v.z + v.w * v.w;
#pragma unroll
  for (int m = 32; m >= 1; m >>= 1) s += __shfl_xor(s, m, 64);
  __shared__ float red[4];
  if ((tid & 63) == 0) red[tid >> 6] = s;
  __syncthreads();
  float tot = red[0] + red[1] + red[2] + red[3];
  float inv = rsqrtf(tot * (1.0f / (float)D_MODEL) + 1e-6f);
  float4 wv = *(const float4*)&w[tid * 4];
  bf16x4 o4 = to_bf4(v.x * inv * wv.x, v.y * inv * wv.y, v.z * inv * wv.z, v.w * inv * wv.w);
  *(bf16x4*)&out[(size_t)row * D_MODEL + tid * 4] = o4;
}

// ---------------------------------------------------------------------------
// Merged per-layer weight transpose+convert (5 weights, one launch per layer).
// ---------------------------------------------------------------------------
__global__ __launch_bounds__(256) void tp5_kernel(
    const float* __restrict__ Wqkv, const float* __restrict__ Wout,
    const float* __restrict__ Wg, const float* __restrict__ Wu,
    const float* __restrict__ Wd,
    __bf16* __restrict__ wqkvT, __bf16* __restrict__ woutT,
    __bf16* __restrict__ wguT, __bf16* __restrict__ wdT) {
  __shared__ __bf16 tile[64][65];
  int t = blockIdx.x;
  const float* in;
  __bf16* out;
  int R, C, Ro, rmul, roff, tr;
  if (t < 768)        { in = Wqkv; out = wqkvT; R = 1024; C = 3072; Ro = 1024; rmul = 1; roff = 0; tr = 16; }
  else if (t < 1024)  { t -= 768;  in = Wout; out = woutT; R = 1024; C = 1024; Ro = 1024; rmul = 1; roff = 0; tr = 16; }
  else if (t < 1728)  { t -= 1024; in = Wg; out = wguT; R = 1024; C = HID; Ro = 1024; rmul = 2; roff = 0; tr = 16; }
  else if (t < 2432)  { t -= 1728; in = Wu; out = wguT; R = 1024; C = HID; Ro = 1024; rmul = 2; roff = 1; tr = 16; }
  else                { t -= 2432; in = Wd; out = wdT; R = HID; C = 1024; Ro = HID_PAD; rmul = 1; roff = 0; tr = 44; }
  int r0 = (t % tr) * 64, c0 = (t / tr) * 64;
  int tid = threadIdx.x;
  bool fullc = (c0 + 64 <= C);
#pragma unroll
  for (int i = 0; i < 4; ++i) {
    int ri = i * 16 + (tid >> 4);
    int ci = (tid & 15) * 4;
    int r = r0 + ri;
    float4 v = {0.f, 0.f, 0.f, 0.f};
    if (r < R) {
      const float* p = in + (size_t)r * C + c0 + ci;
      if (fullc) {
        v = *(const float4*)p;
      } else {
        int c = c0 + ci;
        if (c + 0 < C) v.x = p[0];
        if (c + 1 < C) v.y = p[1];
        if (c + 2 < C) v.z = p[2];
        if (c + 3 < C) v.w = p[3];
      }
    }
    tile[ri][ci + 0] = (__bf16)v.x;
    tile[ri][ci + 1] = (__bf16)v.y;
    tile[ri][ci + 2] = (__bf16)v.z;
    tile[ri][ci + 3] = (__bf16)v.w;
  }
  __syncthreads();
#pragma unroll
  for (int i = 0; i < 4; ++i) {
    int oc = i * 16 + (tid >> 4);
    int orr = (tid & 15) * 4;
    bf16x4 tv;
    tv[0] = tile[orr + 0][oc];
    tv[1] = tile[orr + 1][oc];
    tv[2] = tile[orr + 2][oc];
    tv[3] = tile[orr + 3][oc];
    *(bf16x4*)&out[((size_t)(c0 + oc) * rmul + roff) * Ro + r0 + orr] = tv;
  }
}

// ---------------------------------------------------------------------------
// Plain f32 -> bf16 convert (W_emb)
// ---------------------------------------------------------------------------
__global__ __launch_bounds__(256) void convert_bf16_kernel(const float* __restrict__ in,
                                                           __bf16* __restrict__ out, int n4) {
  for (int i = blockIdx.x * 256 + threadIdx.x; i < n4; i += gridDim.x * 256) {
    float4 v = ((const float4*)in)[i];
    ((bf16x4*)out)[i] = to_bf4(v.x, v.y, v.z, v.w);
  }
}

// ---------------------------------------------------------------------------
// Deep-pipelined GEMM (round-7-proven): C[M,N] = A[M,K] @ B^T, sigma-permuted
// LDS chunks, counted vmcnt, setprio. MF==8 fine sub-phase schedule; other MF
// coarse. EPI: 0 f32, 1 f32+residual, 4 interleaved-g/u fused silu,
// 5 fused qkv postprocess.
// ---------------------------------------------------------------------------
template <int BM, int BN, int WM, int WN, int EPI>
__global__ __launch_bounds__(WM * WN * 64, 2) void gemm8(
    const __bf16* __restrict__ A, const __bf16* __restrict__ B,
    const float* __restrict__ Cin, void* __restrict__ Cout,
    int K, int ldc,
    const float* __restrict__ Tab, __bf16* __restrict__ Qr,
    __bf16* __restrict__ Kr, __bf16* __restrict__ Vt) {
  constexpr int NTH = WM * WN * 64;
  constexpr int MF = BM / (16 * WM);
  constexpr int MG = (MF + 3) / 4;
  constexpr int CL = (MF < 4) ? MF : 4;
  constexpr int LA = (BM * 4) / NTH;
  constexpr int LB = (BN * 4) / NTH;
  static_assert(BN / WN == 64, "NF must be 4");
  static_assert(LA + LB == 2 || LA + LB == 3 || LA + LB == 4, "vmcnt branch coverage");
  __shared__ __align__(16) __bf16 lds[(BM + BN) * 128];

  const int tid = threadIdx.x;
  const int lane = tid & 63, wid = tid >> 6;
  const int wr = wid / WN, wn = wid % WN;
  const int lr = lane & 15, lg = lane >> 4;

  const int gx = gridDim.x;
  const int nwg = gx * gridDim.y;
  const int orig = blockIdx.y * gx + blockIdx.x;
  const int q = nwg >> 3, r8 = nwg & 7;
  const int xcd = orig & 7, loc = orig >> 3;
  const int swz = ((xcd < r8) ? xcd * (q + 1) : r8 * (q + 1) + (xcd - r8) * q) + loc;
  const int brow = (swz % gx) * BM;
  const int bcol = (swz / gx) * BN;

  const __bf16* pAg[LA];
  const __bf16* pBg[LB];
  int opA[LA], opB[LB];
#pragma unroll
  for (int i = 0; i < LA; ++i) {
    int p = tid + i * NTH;
    int row = ((p >> 6) << 4) | (p & 15), j = (p >> 4) & 3;
    pAg[i] = A + (size_t)(brow + row) * K + j * 8;
    opA[i] = p * 8;
  }
#pragma unroll
  for (int i = 0; i < LB; ++i) {
    int p = tid + i * NTH;
    int row = ((p >> 6) << 4) | (p & 15), j = (p >> 4) & 3;
    pBg[i] = B + (size_t)(bcol + row) * K + j * 8;
    opB[i] = p * 8;
  }

  const int ntiles = K >> 6;

  auto STAGE_A = [&](int v, int kkq) {
    int vs = v < ntiles ? v : ntiles - 1;
    int ko = vs * 64 + kkq * 32;
    int sa = (v & 1) * (BM * 64) + kkq * (BM * 32);
#pragma unroll
    for (int i = 0; i < LA; ++i) gload16(pAg[i] + ko, lds + sa + opA[i]);
  };
  auto STAGE_B = [&](int v, int kkq) {
    int vs = v < ntiles ? v : ntiles - 1;
    int ko = vs * 64 + kkq * 32;
    int sb = BM * 128 + (v & 1) * (BN * 64) + kkq * (BN * 32);
#pragma unroll
    for (int i = 0; i < LB; ++i) gload16(pBg[i] + ko, lds + sb + opB[i]);
  };

  f32x4 acc[MF][4];
#pragma unroll
  for (int m = 0; m < MF; ++m)
#pragma unroll
    for (int n = 0; n < 4; ++n) acc[m][n] = (f32x4){0.f, 0.f, 0.f, 0.f};

  STAGE_A(0, 0); STAGE_B(0, 0);
  STAGE_A(0, 1); STAGE_B(0, 1);
  STAGE_A(1, 0); STAGE_B(1, 0);

  const int fragoff = lg * 128 + lr * 8;

  if constexpr (MF == 8) {
    for (int u = 0; u < ntiles; ++u) {
      const int buf = u & 1;
#pragma unroll
      for (int kk = 0; kk < 2; ++kk) {
        const int v = (kk == 0) ? u + 1 : u + 2;
        const int kkq = kk ^ 1;
        const __bf16* Ab = lds + buf * (BM * 64) + kk * (BM * 32);
        const __bf16* Bb = lds + BM * 128 + buf * (BN * 64) + kk * (BN * 32);
        asm volatile("s_waitcnt vmcnt(8)" ::: "memory");
        __builtin_amdgcn_sched_barrier(0);
        __builtin_amdgcn_s_barrier();
        __builtin_amdgcn_sched_barrier(0);
        STAGE_A(v, kkq);
        bf16x8 bfr[4], af0[4];
#pragma unroll
        for (int n = 0; n < 4; ++n)
          bfr[n] = *(const bf16x8*)(Bb + (wn * 64 + n * 16) * 32 + fragoff);
#pragma unroll
        for (int i = 0; i < 4; ++i)
          af0[i] = *(const bf16x8*)(Ab + (wr * 128 + i * 16) * 32 + fragoff);
        asm volatile("s_waitcnt lgkmcnt(0)" ::: "memory");
        __builtin_amdgcn_sched_barrier(0);
        __builtin_amdgcn_s_setprio(1);
#pragma unroll
        for (int i = 0; i < 4; ++i)
#pragma unroll
          for (int n = 0; n < 4; ++n)
            acc[i][n] = __builtin_amdgcn_mfma_f32_16x16x32_bf16(af0[i], bfr[n], acc[i][n], 0, 0, 0);
        __builtin_amdgcn_s_setprio(0);
        __builtin_amdgcn_s_barrier();
        STAGE_B(v, kkq);
        bf16x8 af1[4];
#pragma unroll
        for (int i = 0; i < 4; ++i)
          af1[i] = *(const bf16x8*)(Ab + (wr * 128 + 64 + i * 16) * 32 + fragoff);
        asm volatile("s_waitcnt lgkmcnt(0)" ::: "memory");
        __builtin_amdgcn_sched_barrier(0);
        __builtin_amdgcn_s_setprio(1);
#pragma unroll
        for (int i = 0; i < 4; ++i)
#pragma unroll
          for (int n = 0; n < 4; ++n)
            acc[4 + i][n] = __builtin_amdgcn_mfma_f32_16x16x32_bf16(af1[i], bfr[n], acc[4 + i][n], 0, 0, 0);
        __builtin_amdgcn_s_setprio(0);
        __builtin_amdgcn_s_barrier();
      }
    }
  } else {
    for (int u = 0; u < ntiles; ++u) {
      const int buf = u & 1;
#pragma unroll
      for (int kk = 0; kk < 2; ++kk) {
        if constexpr (LA + LB == 2)      asm volatile("s_waitcnt vmcnt(4)" ::: "memory");
        else if constexpr (LA + LB == 3) asm volatile("s_waitcnt vmcnt(6)" ::: "memory");
        else                             asm volatile("s_waitcnt vmcnt(8)" ::: "memory");
        __builtin_amdgcn_sched_barrier(0);
        __builtin_amdgcn_s_barrier();
        __builtin_amdgcn_sched_barrier(0);
        const int v = (kk == 0) ? u + 1 : u + 2;
        const int kkq = kk ^ 1;
        STAGE_A(v, kkq);
        STAGE_B(v, kkq);
        const __bf16* Ab = lds + buf * (BM * 64) + kk * (BM * 32);
        const __bf16* Bb = lds + BM * 128 + buf * (BN * 64) + kk * (BN * 32);
        bf16x8 bfr[4];
#pragma unroll
        for (int n = 0; n < 4; ++n)
          bfr[n] = *(const bf16x8*)(Bb + (wn * 64 + n * 16) * 32 + fragoff);
#pragma unroll
        for (int mg = 0; mg < MG; ++mg) {
          bf16x8 afr[CL];
#pragma unroll
          for (int i = 0; i < CL; ++i)
            afr[i] = *(const bf16x8*)(Ab + (wr * (BM / WM) + (mg * 4 + i) * 16) * 32 + fragoff);
          __builtin_amdgcn_s_setprio(1);
#pragma unroll
          for (int i = 0; i < CL; ++i)
#pragma unroll
            for (int n = 0; n < 4; ++n)
              acc[mg * 4 + i][n] =
                  __builtin_amdgcn_mfma_f32_16x16x32_bf16(afr[i], bfr[n], acc[mg * 4 + i][n], 0, 0, 0);
          __builtin_amdgcn_s_setprio(0);
        }
      }
    }
  }

  if constexpr (EPI == 5) {
    const int colw = bcol + wn * 64;
    const int secw = colw >> 10;          // 0=q 1=k 2=v
    const int h = (colw >> 6) & 15;
#pragma unroll
    for (int m = 0; m < MF; ++m) {
      int row0 = brow + wr * (BM / WM) + m * 16 + lg * 4;
      int bb = row0 >> 10;
      int t0 = row0 & 1023;
      int bh = bb * 16 + h;
      if (secw < 2) {
        __bf16* base = (secw == 0 ? Qr : Kr) + ((size_t)bh * T_SEQ + t0) * 64;
#pragma unroll
        for (int n = 0; n < 2; ++n) {
          int din = n * 16 + lr;
#pragma unroll
          for (int rr = 0; rr < 4; ++rr) {
            float a = acc[m][n][rr], b2 = acc[m][n + 2][rr];
            float cs = Tab[(t0 + rr) * 32 + din];
            float sn = Tab[32768 + (t0 + rr) * 32 + din];
            base[(size_t)rr * 64 + din]      = (__bf16)(a * cs - b2 * sn);
            base[(size_t)rr * 64 + din + 32] = (__bf16)(a * sn + b2 * cs);
          }
        }
      } else {
#pragma unroll
        for (int n = 0; n < 4; ++n) {
          int din = n * 16 + lr;
          bf16x4 pk;
#pragma unroll
          for (int rr = 0; rr < 4; ++rr) pk[rr] = (__bf16)acc[m][n][rr];
          *(bf16x4*)&Vt[((size_t)bh * 64 + din) * T_SEQ + t0] = pk;
        }
      }
    }
  } else {
#pragma unroll
    for (int m = 0; m < MF; ++m) {
#pragma unroll
      for (int n = 0; n < 4; ++n) {
#pragma unroll
        for (int rr = 0; rr < 4; ++rr) {
          int row = brow + wr * (BM / WM) + m * 16 + lg * 4 + rr;
          int col = bcol + wn * 64 + n * 16 + lr;
          size_t off = (size_t)row * ldc + col;
          float vv = acc[m][n][rr];
          if (EPI == 0) {
            ((float*)Cout)[off] = vv;
          } else if (EPI == 1) {
            ((float*)Cout)[off] = Cin[off] + vv;
          } else {
            float uv = __shfl_xor(vv, 1);
            if ((lr & 1) == 0) {
              float r = vv / (1.f + __expf(-vv)) * uv;
              ((__bf16*)Cout)[(size_t)row * ldc + (col >> 1)] = (__bf16)r;
            }
          }
        }
      }
    }
  }
}

// ---------------------------------------------------------------------------
// Flash attention, causal-balanced (round-7-proven): block (qp, bh) handles
// q-blocks qp and 15-qp. 4 waves x 16 q-rows, KVBLK=128.
// ---------------------------------------------------------------------------
__global__ __launch_bounds__(256) void attn_kernel(const __bf16* __restrict__ Qr,
                                                   const __bf16* __restrict__ Kr,
                                                   const __bf16* __restrict__ Vt,
                                                   __bf16* __restrict__ o) {
  __shared__ __align__(16) __bf16 lds[28672];
  const int tid = threadIdx.x;
  const int lane = tid & 63, w = tid >> 6;
  const int lr = lane & 15, lg = lane >> 4;
  const int bh = blockIdx.y, b = bh >> 4, h = bh & 15;
  const int qp = blockIdx.x;
  const __bf16* Kg = Kr + (size_t)bh * T_SEQ * 64;
  const __bf16* Vg = Vt + (size_t)bh * 64 * T_SEQ;
  const float scale = 0.125f;
  __bf16* Pw = lds + 20480 + w * 2048;

  for (int qs = 0; qs < 2; ++qs) {
    const int qb = qs ? (15 - qp) : qp;
    const int q0 = qb * 64;
    const __bf16* Qg = Qr + ((size_t)bh * T_SEQ + q0) * 64;

    __syncthreads();
    {
      int row = ((tid >> 6) << 4) | (tid & 15);
      int j = (tid >> 4) & 3;
      gload16(Qg + row * 64 + j * 8, lds + tid * 8);
      gload16(Qg + row * 64 + 32 + j * 8, lds + 2048 + tid * 8);
    }

    f32x4 accO[4];
#pragma unroll
    for (int n = 0; n < 4; ++n) accO[n] = (f32x4){0.f, 0.f, 0.f, 0.f};
    float mrow[4], lrow[4];
#pragma unroll
    for (int r = 0; r < 4; ++r) { mrow[r] = -1e30f; lrow[r] = 0.f; }

    const int ntile = ((q0 + 63) >> 7) + 1;

    for (int tt = 0; tt < ntile; ++tt) {
      const int j0 = tt * 128;
      __syncthreads();
#pragma unroll
      for (int i = 0; i < 2; ++i) {
        int p = tid + i * 256;
        int row = ((p >> 6) << 4) | (p & 15), j = (p >> 4) & 3;
        const __bf16* src = Kg + (size_t)(j0 + row) * 64 + j * 8;
        gload16(src, lds + 4096 + p * 8);
        gload16(src + 32, lds + 8192 + p * 8);
      }
#pragma unroll
      for (int s = 0; s < 4; ++s) {
        int d = ((tid >> 6) << 4) | (tid & 15), j = (tid >> 4) & 3;
        gload16(Vg + (size_t)d * T_SEQ + j0 + s * 32 + j * 8, lds + 12288 + s * 2048 + tid * 8);
      }
      __syncthreads();

      f32x4 s4[8];
#pragma unroll
      for (int n = 0; n < 8; ++n) s4[n] = (f32x4){0.f, 0.f, 0.f, 0.f};
#pragma unroll
      for (int kk = 0; kk < 2; ++kk) {
        bf16x8 aq = *(const bf16x8*)(lds + kk * 2048 + (w * 64 + lg * 16 + lr) * 8);
        __builtin_amdgcn_s_setprio(1);
#pragma unroll
        for (int jf = 0; jf < 8; ++jf) {
          bf16x8 bk = *(const bf16x8*)(lds + 4096 + kk * 4096 + (jf * 64 + lg * 16 + lr) * 8);
          s4[jf] = __builtin_amdgcn_mfma_f32_16x16x32_bf16(aq, bk, s4[jf], 0, 0, 0);
        }
        __builtin_amdgcn_s_setprio(0);
      }

      float pm[4];
#pragma unroll
      for (int r = 0; r < 4; ++r) pm[r] = -1e30f;
#pragma unroll
      for (int jf = 0; jf < 8; ++jf) {
        int gj = j0 + jf * 16 + lr;
#pragma unroll
        for (int r = 0; r < 4; ++r) {
          int gq = q0 + w * 16 + lg * 4 + r;
          float sv = s4[jf][r] * scale;
          if (gj > gq) sv = -1e30f;
          s4[jf][r] = sv;
          pm[r] = fmaxf(pm[r], sv);
        }
      }
#pragma unroll
      for (int r = 0; r < 4; ++r) {
#pragma unroll
        for (int m = 8; m >= 1; m >>= 1) pm[r] = fmaxf(pm[r], __shfl_xor(pm[r], m, 64));
      }
      float alpha[4];
#pragma unroll
      for (int r = 0; r < 4; ++r) {
        float mn = fmaxf(mrow[r], pm[r]);
        alpha[r] = expf(mrow[r] - mn);
        mrow[r] = mn;
      }
      float ps[4] = {0.f, 0.f, 0.f, 0.f};
#pragma unroll
      for (int jf = 0; jf < 8; ++jf) {
#pragma unroll
        for (int r = 0; r < 4; ++r) {
          float p = expf(s4[jf][r] - mrow[r]);
          s4[jf][r] = p;
          ps[r] += p;
        }
      }
#pragma unroll
      for (int r = 0; r < 4; ++r) {
#pragma unroll
        for (int m = 8; m >= 1; m >>= 1) ps[r] += __shfl_xor(ps[r], m, 64);
        lrow[r] = lrow[r] * alpha[r] + ps[r];
      }
#pragma unroll
      for (int n = 0; n < 4; ++n) {
#pragma unroll
        for (int r = 0; r < 4; ++r) accO[n][r] *= alpha[r];
      }

#pragma unroll
      for (int jf = 0; jf < 8; ++jf) {
        int s = jf >> 1;
        int rem = ((jf & 1) << 4) + lr;
        int base = s * 512 + (rem >> 3) * 128 + (rem & 7);
#pragma unroll
        for (int r = 0; r < 4; ++r) {
          int qloc = lg * 4 + r;
          Pw[base + qloc * 8] = (__bf16)s4[jf][r];
        }
      }
      asm volatile("s_waitcnt lgkmcnt(0)" ::: "memory");
      __builtin_amdgcn_sched_barrier(0);

#pragma unroll
      for (int s = 0; s < 4; ++s) {
        bf16x8 pa = *(const bf16x8*)(Pw + s * 512 + (lg * 16 + lr) * 8);
        __builtin_amdgcn_s_setprio(1);
#pragma unroll
        for (int nd = 0; nd < 4; ++nd) {
          bf16x8 bv = *(const bf16x8*)(lds + 12288 + s * 2048 + (nd * 64 + lg * 16 + lr) * 8);
          accO[nd] = __builtin_amdgcn_mfma_f32_16x16x32_bf16(pa, bv, accO[nd], 0, 0, 0);
        }
        __builtin_amdgcn_s_setprio(0);
      }
    }

#pragma unroll
    for (int nd = 0; nd < 4; ++nd) {
#pragma unroll
      for (int r = 0; r < 4; ++r) {
        int gq = q0 + w * 16 + lg * 4 + r;
        float val = accO[nd][r] / lrow[r];
        o[(size_t)(b * T_SEQ + gq) * D_MODEL + h * 64 + nd * 16 + lr] = (__bf16)val;
      }
    }
  }
}

// ---------------------------------------------------------------------------
extern "C" void kernel_launch(void* const* d_in, const int* in_sizes, int n_in,
                              void* d_out, int out_size, void* d_ws, size_t ws_size,
                              hipStream_t stream) {
  const int*   idx     = (const int*)d_in[0];
  const float* W_emb   = (const float*)d_in[1];
  const float* norm1_w = (const float*)d_in[2];
  const float* Wqkv    = (const float*)d_in[3];
  const float* Wout    = (const float*)d_in[4];
  const float* norm2_w = (const float*)d_in[5];
  const float* Wg      = (const float*)d_in[6];
  const float* Wu      = (const float*)d_in[7];
  const float* Wd      = (const float*)d_in[8];
  const float* fnorm   = (const float*)d_in[9];
  float* out = (float*)d_out;

  float*  x    = (float*)d_ws;                              // 2048*1024 f32
  float*  tab  = x + (size_t)NTOK * D_MODEL;                // 2*32768 f32
  __bf16* hb   = (__bf16*)(tab + 2 * 32768);                // 2048*1024
  __bf16* ob   = hb + (size_t)NTOK * D_MODEL;               // 2048*1024
  __bf16* ga   = ob + (size_t)NTOK * D_MODEL;               // 2048*2816
  __bf16* Qrb  = ga + (size_t)NTOK * HID_PAD;               // 32*1024*64
  __bf16* Krb  = Qrb + (size_t)32 * T_SEQ * 64;
  __bf16* Vtb  = Krb + (size_t)32 * T_SEQ * 64;
  __bf16* wbuf = Vtb + (size_t)32 * T_SEQ * 64;

  __bf16* wqkvT = wbuf;                                     // [3072][1024]
  __bf16* woutT = wqkvT + (size_t)3 * D_MODEL * D_MODEL;    // [1024][1024]
  __bf16* wguT  = woutT + (size_t)D_MODEL * D_MODEL;        // [5632][1024]
  __bf16* wdT   = wguT + (size_t)2 * HID_PAD * D_MODEL;     // [1024][2816]

  embed_rope_kernel<<<NTOK + 128, 256, 0, stream>>>(idx, W_emb, x, tab);

  for (int l = 0; l < NLAYER; ++l) {
    tp5_kernel<<<3136, 256, 0, stream>>>(
        Wqkv + (size_t)l * D_MODEL * 3 * D_MODEL,
        Wout + (size_t)l * D_MODEL * D_MODEL,
        Wg + (size_t)l * D_MODEL * HID,
        Wu + (size_t)l * D_MODEL * HID,
        Wd + (size_t)l * HID * D_MODEL,
        wqkvT, woutT, wguT, wdT);

    rmsnorm_kernel<<<NTOK, 256, 0, stream>>>(x, norm1_w + (size_t)l * D_MODEL, hb);
    gemm8<128, 256, 2, 4, 5><<<dim3(16, 12), 512, 0, stream>>>(
        hb, wqkvT, nullptr, nullptr, D_MODEL, 3 * D_MODEL, tab, Qrb, Krb, Vtb);
    attn_kernel<<<dim3(8, 32), 256, 0, stream>>>(Qrb, Krb, Vtb, ob);
    gemm8<64, 64, 4, 1, 1><<<dim3(32, 16), 256, 0, stream>>>(
        ob, woutT, x, x, D_MODEL, D_MODEL, nullptr, nullptr, nullptr, nullptr);
    rmsnorm_kernel<<<NTOK, 256, 0, stream>>>(x, norm2_w + (size_t)l * D_MODEL, hb);
    gemm8<128, 256, 2, 4, 4><<<dim3(16, 22), 512, 0, stream>>>(
        hb, wguT, nullptr, ga, D_MODEL, HID_PAD, nullptr, nullptr, nullptr, nullptr);
    gemm8<64, 64, 4, 1, 1><<<dim3(32, 16), 256, 0, stream>>>(
        ga, wdT, x, x, HID_PAD, D_MODEL, nullptr, nullptr, nullptr, nullptr);
  }

  rmsnorm_kernel<<<NTOK, 256, 0, stream>>>(x, fnorm, hb);
  convert_bf16_kernel<<<2048, 256, 0, stream>>>(W_emb, wbuf, VOCAB * D_MODEL / 4);
  gemm8<256, 256, 2, 4, 0><<<dim3(8, 125), 512, 0, stream>>>(
      hb, wbuf, nullptr, out, D_MODEL, VOCAB, nullptr, nullptr, nullptr, nullptr);
}

// Round 14
// 1845.708 us; speedup vs baseline: 1.0539x; 1.0539x over previous
//
#include <hip/hip_runtime.h>
#include <cstdint>
#include <cmath>

#define D_MODEL 1024
#define T_SEQ   1024
#define NHEAD   16
#define NLAYER  8
#define HID     2734
#define HID_PAD 2816
#define NTOK    2048
#define VOCAB   32000

typedef __bf16 bf16x8 __attribute__((ext_vector_type(8)));
typedef __bf16 bf16x4 __attribute__((ext_vector_type(4)));
typedef float  f32x4  __attribute__((ext_vector_type(4)));

__device__ inline bf16x4 to_bf4(float a, float b, float c, float d) {
  bf16x4 t; t[0] = (__bf16)a; t[1] = (__bf16)b; t[2] = (__bf16)c; t[3] = (__bf16)d; return t;
}

__device__ inline void gload16(const __bf16* g, __bf16* l) {
  __builtin_amdgcn_global_load_lds(
      (const __attribute__((address_space(1))) void*)g,
      (__attribute__((address_space(3))) void*)l, 16, 0, 0);
}

// ---------------------------------------------------------------------------
// Embedding gather
// ---------------------------------------------------------------------------
__global__ __launch_bounds__(256) void embed_kernel(const int* __restrict__ idx,
                                                    const float* __restrict__ W,
                                                    float* __restrict__ x) {
  int t = blockIdx.x;
  int v = idx[t];
  float4 val = *(const float4*)&W[(size_t)v * D_MODEL + threadIdx.x * 4];
  *(float4*)&x[(size_t)t * D_MODEL + threadIdx.x * 4] = val;
}

// ---------------------------------------------------------------------------
// RMSNorm: f32 in -> bf16 out
// ---------------------------------------------------------------------------
__global__ __launch_bounds__(256) void rmsnorm_kernel(const float* __restrict__ x,
                                                      const float* __restrict__ w,
                                                      __bf16* __restrict__ out) {
  int row = blockIdx.x;
  int tid = threadIdx.x;
  float4 v = *(const float4*)&x[(size_t)row * D_MODEL + tid * 4];
  float s = v.x * v.x + v.y * v.y + v.z * v.z + v.w * v.w;
#pragma unroll
  for (int m = 32; m >= 1; m >>= 1) s += __shfl_xor(s, m, 64);
  __shared__ float red[4];
  if ((tid & 63) == 0) red[tid >> 6] = s;
  __syncthreads();
  float tot = red[0] + red[1] + red[2] + red[3];
  float inv = rsqrtf(tot * (1.0f / (float)D_MODEL) + 1e-6f);
  float4 wv = *(const float4*)&w[tid * 4];
  bf16x4 o4 = to_bf4(v.x * inv * wv.x, v.y * inv * wv.y, v.z * inv * wv.z, v.w * inv * wv.w);
  *(bf16x4*)&out[(size_t)row * D_MODEL + tid * 4] = o4;
}

// ---------------------------------------------------------------------------
// RoPE cos/sin table
// ---------------------------------------------------------------------------
__global__ __launch_bounds__(256) void rope_table_kernel(float* __restrict__ tab) {
  int p = blockIdx.x * 256 + threadIdx.x;
  int t = p >> 5, i = p & 31;
  float freq = exp2f(-(float)i * (13.287712379549449f / 32.0f));
  float sn, cs;
  sincosf((float)t * freq, &sn, &cs);
  tab[p] = cs;
  tab[32768 + p] = sn;
}

// ---------------------------------------------------------------------------
// Merged per-layer weight transpose+convert (5 weights, one launch).
// ---------------------------------------------------------------------------
__global__ __launch_bounds__(256) void tp5_kernel(
    const float* __restrict__ Wqkv, const float* __restrict__ Wout,
    const float* __restrict__ Wg, const float* __restrict__ Wu,
    const float* __restrict__ Wd,
    __bf16* __restrict__ wqkvT, __bf16* __restrict__ woutT,
    __bf16* __restrict__ wguT, __bf16* __restrict__ wdT) {
  __shared__ __bf16 tile[64][65];
  int t = blockIdx.x;
  const float* in;
  __bf16* out;
  int R, C, Ro, rmul, roff, tr;
  if (t < 768)        { in = Wqkv; out = wqkvT; R = 1024; C = 3072; Ro = 1024; rmul = 1; roff = 0; tr = 16; }
  else if (t < 1024)  { t -= 768;  in = Wout; out = woutT; R = 1024; C = 1024; Ro = 1024; rmul = 1; roff = 0; tr = 16; }
  else if (t < 1728)  { t -= 1024; in = Wg; out = wguT; R = 1024; C = HID; Ro = 1024; rmul = 2; roff = 0; tr = 16; }
  else if (t < 2432)  { t -= 1728; in = Wu; out = wguT; R = 1024; C = HID; Ro = 1024; rmul = 2; roff = 1; tr = 16; }
  else                { t -= 2432; in = Wd; out = wdT; R = HID; C = 1024; Ro = HID_PAD; rmul = 1; roff = 0; tr = 44; }
  int r0 = (t % tr) * 64, c0 = (t / tr) * 64;
  int tid = threadIdx.x;
  bool fullc = (c0 + 64 <= C);
#pragma unroll
  for (int i = 0; i < 4; ++i) {
    int ri = i * 16 + (tid >> 4);
    int ci = (tid & 15) * 4;
    int r = r0 + ri;
    float4 v = {0.f, 0.f, 0.f, 0.f};
    if (r < R) {
      const float* p = in + (size_t)r * C + c0 + ci;
      if (fullc) {
        v = *(const float4*)p;
      } else {
        int c = c0 + ci;
        if (c + 0 < C) v.x = p[0];
        if (c + 1 < C) v.y = p[1];
        if (c + 2 < C) v.z = p[2];
        if (c + 3 < C) v.w = p[3];
      }
    }
    tile[ri][ci + 0] = (__bf16)v.x;
    tile[ri][ci + 1] = (__bf16)v.y;
    tile[ri][ci + 2] = (__bf16)v.z;
    tile[ri][ci + 3] = (__bf16)v.w;
  }
  __syncthreads();
#pragma unroll
  for (int i = 0; i < 4; ++i) {
    int oc = i * 16 + (tid >> 4);
    int orr = (tid & 15) * 4;
    bf16x4 tv;
    tv[0] = tile[orr + 0][oc];
    tv[1] = tile[orr + 1][oc];
    tv[2] = tile[orr + 2][oc];
    tv[3] = tile[orr + 3][oc];
    *(bf16x4*)&out[((size_t)(c0 + oc) * rmul + roff) * Ro + r0 + orr] = tv;
  }
}

// ---------------------------------------------------------------------------
// Plain f32 -> bf16 convert (W_emb)
// ---------------------------------------------------------------------------
__global__ __launch_bounds__(256) void convert_bf16_kernel(const float* __restrict__ in,
                                                           __bf16* __restrict__ out, int n4) {
  for (int i = blockIdx.x * 256 + threadIdx.x; i < n4; i += gridDim.x * 256) {
    float4 v = ((const float4*)in)[i];
    ((bf16x4*)out)[i] = to_bf4(v.x, v.y, v.z, v.w);
  }
}

// ---------------------------------------------------------------------------
// Deep-pipelined GEMM: C[M,N] = A[M,K] @ B^T, sigma-permuted LDS chunks,
// counted vmcnt, setprio. MF==8 fine sub-phase schedule; other MF coarse.
// EPI: 0 f32, 1 f32+residual, 4 interleaved-g/u fused silu (bf16, cols
// halved), 5 fused qkv postprocess: rope(q)->Qr, rope(k)->Kr, v^T->Vt.
// ---------------------------------------------------------------------------
template <int BM, int BN, int WM, int WN, int EPI>
__global__ __launch_bounds__(WM * WN * 64, 2) void gemm8(
    const __bf16* __restrict__ A, const __bf16* __restrict__ B,
    const float* __restrict__ Cin, void* __restrict__ Cout,
    int K, int ldc,
    const float* __restrict__ Tab, __bf16* __restrict__ Qr,
    __bf16* __restrict__ Kr, __bf16* __restrict__ Vt) {
  constexpr int NTH = WM * WN * 64;
  constexpr int MF = BM / (16 * WM);
  constexpr int MG = (MF + 3) / 4;
  constexpr int CL = (MF < 4) ? MF : 4;
  constexpr int LA = (BM * 4) / NTH;
  constexpr int LB = (BN * 4) / NTH;
  static_assert(BN / WN == 64, "NF must be 4");
  __shared__ __align__(16) __bf16 lds[(BM + BN) * 128];

  const int tid = threadIdx.x;
  const int lane = tid & 63, wid = tid >> 6;
  const int wr = wid / WN, wn = wid % WN;
  const int lr = lane & 15, lg = lane >> 4;

  const int gx = gridDim.x;
  const int nwg = gx * gridDim.y;
  const int orig = blockIdx.y * gx + blockIdx.x;
  const int q = nwg >> 3, r8 = nwg & 7;
  const int xcd = orig & 7, loc = orig >> 3;
  const int swz = ((xcd < r8) ? xcd * (q + 1) : r8 * (q + 1) + (xcd - r8) * q) + loc;
  const int brow = (swz % gx) * BM;
  const int bcol = (swz / gx) * BN;

  const __bf16* pAg[LA];
  const __bf16* pBg[LB];
  int opA[LA], opB[LB];
#pragma unroll
  for (int i = 0; i < LA; ++i) {
    int p = tid + i * NTH;
    int row = ((p >> 6) << 4) | (p & 15), j = (p >> 4) & 3;
    pAg[i] = A + (size_t)(brow + row) * K + j * 8;
    opA[i] = p * 8;
  }
#pragma unroll
  for (int i = 0; i < LB; ++i) {
    int p = tid + i * NTH;
    int row = ((p >> 6) << 4) | (p & 15), j = (p >> 4) & 3;
    pBg[i] = B + (size_t)(bcol + row) * K + j * 8;
    opB[i] = p * 8;
  }

  const int ntiles = K >> 6;

  auto STAGE_A = [&](int v, int kkq) {
    int vs = v < ntiles ? v : ntiles - 1;
    int ko = vs * 64 + kkq * 32;
    int sa = (v & 1) * (BM * 64) + kkq * (BM * 32);
#pragma unroll
    for (int i = 0; i < LA; ++i) gload16(pAg[i] + ko, lds + sa + opA[i]);
  };
  auto STAGE_B = [&](int v, int kkq) {
    int vs = v < ntiles ? v : ntiles - 1;
    int ko = vs * 64 + kkq * 32;
    int sb = BM * 128 + (v & 1) * (BN * 64) + kkq * (BN * 32);
#pragma unroll
    for (int i = 0; i < LB; ++i) gload16(pBg[i] + ko, lds + sb + opB[i]);
  };

  f32x4 acc[MF][4];
#pragma unroll
  for (int m = 0; m < MF; ++m)
#pragma unroll
    for (int n = 0; n < 4; ++n) acc[m][n] = (f32x4){0.f, 0.f, 0.f, 0.f};

  STAGE_A(0, 0); STAGE_B(0, 0);
  STAGE_A(0, 1); STAGE_B(0, 1);
  STAGE_A(1, 0); STAGE_B(1, 0);

  const int fragoff = lg * 128 + lr * 8;

  if constexpr (MF == 8) {
    for (int u = 0; u < ntiles; ++u) {
      const int buf = u & 1;
#pragma unroll
      for (int kk = 0; kk < 2; ++kk) {
        const int v = (kk == 0) ? u + 1 : u + 2;
        const int kkq = kk ^ 1;
        const __bf16* Ab = lds + buf * (BM * 64) + kk * (BM * 32);
        const __bf16* Bb = lds + BM * 128 + buf * (BN * 64) + kk * (BN * 32);
        asm volatile("s_waitcnt vmcnt(8)" ::: "memory");
        __builtin_amdgcn_sched_barrier(0);
        __builtin_amdgcn_s_barrier();
        __builtin_amdgcn_sched_barrier(0);
        STAGE_A(v, kkq);
        bf16x8 bfr[4], af0[4];
#pragma unroll
        for (int n = 0; n < 4; ++n)
          bfr[n] = *(const bf16x8*)(Bb + (wn * 64 + n * 16) * 32 + fragoff);
#pragma unroll
        for (int i = 0; i < 4; ++i)
          af0[i] = *(const bf16x8*)(Ab + (wr * 128 + i * 16) * 32 + fragoff);
        asm volatile("s_waitcnt lgkmcnt(0)" ::: "memory");
        __builtin_amdgcn_sched_barrier(0);
        __builtin_amdgcn_s_setprio(1);
#pragma unroll
        for (int i = 0; i < 4; ++i)
#pragma unroll
          for (int n = 0; n < 4; ++n)
            acc[i][n] = __builtin_amdgcn_mfma_f32_16x16x32_bf16(af0[i], bfr[n], acc[i][n], 0, 0, 0);
        __builtin_amdgcn_s_setprio(0);
        __builtin_amdgcn_s_barrier();
        STAGE_B(v, kkq);
        bf16x8 af1[4];
#pragma unroll
        for (int i = 0; i < 4; ++i)
          af1[i] = *(const bf16x8*)(Ab + (wr * 128 + 64 + i * 16) * 32 + fragoff);
        asm volatile("s_waitcnt lgkmcnt(0)" ::: "memory");
        __builtin_amdgcn_sched_barrier(0);
        __builtin_amdgcn_s_setprio(1);
#pragma unroll
        for (int i = 0; i < 4; ++i)
#pragma unroll
          for (int n = 0; n < 4; ++n)
            acc[4 + i][n] = __builtin_amdgcn_mfma_f32_16x16x32_bf16(af1[i], bfr[n], acc[4 + i][n], 0, 0, 0);
        __builtin_amdgcn_s_setprio(0);
        __builtin_amdgcn_s_barrier();
      }
    }
  } else {
    for (int u = 0; u < ntiles; ++u) {
      const int buf = u & 1;
#pragma unroll
      for (int kk = 0; kk < 2; ++kk) {
        if constexpr (LA + LB == 3) asm volatile("s_waitcnt vmcnt(6)" ::: "memory");
        else                        asm volatile("s_waitcnt vmcnt(8)" ::: "memory");
        __builtin_amdgcn_sched_barrier(0);
        __builtin_amdgcn_s_barrier();
        __builtin_amdgcn_sched_barrier(0);
        const int v = (kk == 0) ? u + 1 : u + 2;
        const int kkq = kk ^ 1;
        STAGE_A(v, kkq);
        STAGE_B(v, kkq);
        const __bf16* Ab = lds + buf * (BM * 64) + kk * (BM * 32);
        const __bf16* Bb = lds + BM * 128 + buf * (BN * 64) + kk * (BN * 32);
        bf16x8 bfr[4];
#pragma unroll
        for (int n = 0; n < 4; ++n)
          bfr[n] = *(const bf16x8*)(Bb + (wn * 64 + n * 16) * 32 + fragoff);
#pragma unroll
        for (int mg = 0; mg < MG; ++mg) {
          bf16x8 afr[CL];
#pragma unroll
          for (int i = 0; i < CL; ++i)
            afr[i] = *(const bf16x8*)(Ab + (wr * (BM / WM) + (mg * 4 + i) * 16) * 32 + fragoff);
          __builtin_amdgcn_s_setprio(1);
#pragma unroll
          for (int i = 0; i < CL; ++i)
#pragma unroll
            for (int n = 0; n < 4; ++n)
              acc[mg * 4 + i][n] =
                  __builtin_amdgcn_mfma_f32_16x16x32_bf16(afr[i], bfr[n], acc[mg * 4 + i][n], 0, 0, 0);
          __builtin_amdgcn_s_setprio(0);
        }
      }
    }
  }

  if constexpr (EPI == 5) {
    // fused qkv postprocess. Wave's 64 cols = one head slice.
    const int colw = bcol + wn * 64;
    const int secw = colw >> 10;          // 0=q 1=k 2=v
    const int h = (colw >> 6) & 15;
#pragma unroll
    for (int m = 0; m < MF; ++m) {
      int row0 = brow + wr * (BM / WM) + m * 16 + lg * 4;
      int bb = row0 >> 10;
      int t0 = row0 & 1023;
      int bh = bb * 16 + h;
      if (secw < 2) {
        __bf16* base = (secw == 0 ? Qr : Kr) + ((size_t)bh * T_SEQ + t0) * 64;
#pragma unroll
        for (int n = 0; n < 2; ++n) {
          int din = n * 16 + lr;
#pragma unroll
          for (int rr = 0; rr < 4; ++rr) {
            float a = acc[m][n][rr], b2 = acc[m][n + 2][rr];
            float cs = Tab[(t0 + rr) * 32 + din];
            float sn = Tab[32768 + (t0 + rr) * 32 + din];
            base[(size_t)rr * 64 + din]      = (__bf16)(a * cs - b2 * sn);
            base[(size_t)rr * 64 + din + 32] = (__bf16)(a * sn + b2 * cs);
          }
        }
      } else {
#pragma unroll
        for (int n = 0; n < 4; ++n) {
          int din = n * 16 + lr;
          bf16x4 pk;
#pragma unroll
          for (int rr = 0; rr < 4; ++rr) pk[rr] = (__bf16)acc[m][n][rr];
          *(bf16x4*)&Vt[((size_t)bh * 64 + din) * T_SEQ + t0] = pk;
        }
      }
    }
  } else {
#pragma unroll
    for (int m = 0; m < MF; ++m) {
#pragma unroll
      for (int n = 0; n < 4; ++n) {
#pragma unroll
        for (int rr = 0; rr < 4; ++rr) {
          int row = brow + wr * (BM / WM) + m * 16 + lg * 4 + rr;
          int col = bcol + wn * 64 + n * 16 + lr;
          size_t off = (size_t)row * ldc + col;
          float vv = acc[m][n][rr];
          if (EPI == 0) {
            ((float*)Cout)[off] = vv;
          } else if (EPI == 1) {
            ((float*)Cout)[off] = Cin[off] + vv;
          } else {
            float uv = __shfl_xor(vv, 1);
            if ((lr & 1) == 0) {
              float r = vv / (1.f + __expf(-vv)) * uv;
              ((__bf16*)Cout)[(size_t)row * ldc + (col >> 1)] = (__bf16)r;
            }
          }
        }
      }
    }
  }
}

// ---------------------------------------------------------------------------
// Flash attention, causal-balanced: block (qp, bh) handles q-blocks qp and
// 15-qp (work = 9 kv-tiles each pair). 4 waves x 16 q-rows, KVBLK=128.
// ---------------------------------------------------------------------------
__global__ __launch_bounds__(256) void attn_kernel(const __bf16* __restrict__ Qr,
                                                   const __bf16* __restrict__ Kr,
                                                   const __bf16* __restrict__ Vt,
                                                   __bf16* __restrict__ o) {
  __shared__ __align__(16) __bf16 lds[28672];
  const int tid = threadIdx.x;
  const int lane = tid & 63, w = tid >> 6;
  const int lr = lane & 15, lg = lane >> 4;
  const int bh = blockIdx.y, b = bh >> 4, h = bh & 15;
  const int qp = blockIdx.x;
  const __bf16* Kg = Kr + (size_t)bh * T_SEQ * 64;
  const __bf16* Vg = Vt + (size_t)bh * 64 * T_SEQ;
  const float scale = 0.125f;
  __bf16* Pw = lds + 20480 + w * 2048;

  for (int qs = 0; qs < 2; ++qs) {
    const int qb = qs ? (15 - qp) : qp;
    const int q0 = qb * 64;
    const __bf16* Qg = Qr + ((size_t)bh * T_SEQ + q0) * 64;

    __syncthreads();
    {
      int row = ((tid >> 6) << 4) | (tid & 15);
      int j = (tid >> 4) & 3;
      gload16(Qg + row * 64 + j * 8, lds + tid * 8);
      gload16(Qg + row * 64 + 32 + j * 8, lds + 2048 + tid * 8);
    }

    f32x4 accO[4];
#pragma unroll
    for (int n = 0; n < 4; ++n) accO[n] = (f32x4){0.f, 0.f, 0.f, 0.f};
    float mrow[4], lrow[4];
#pragma unroll
    for (int r = 0; r < 4; ++r) { mrow[r] = -1e30f; lrow[r] = 0.f; }

    const int ntile = ((q0 + 63) >> 7) + 1;

    for (int tt = 0; tt < ntile; ++tt) {
      const int j0 = tt * 128;
      __syncthreads();
#pragma unroll
      for (int i = 0; i < 2; ++i) {
        int p = tid + i * 256;
        int row = ((p >> 6) << 4) | (p & 15), j = (p >> 4) & 3;
        const __bf16* src = Kg + (size_t)(j0 + row) * 64 + j * 8;
        gload16(src, lds + 4096 + p * 8);
        gload16(src + 32, lds + 8192 + p * 8);
      }
#pragma unroll
      for (int s = 0; s < 4; ++s) {
        int d = ((tid >> 6) << 4) | (tid & 15), j = (tid >> 4) & 3;
        gload16(Vg + (size_t)d * T_SEQ + j0 + s * 32 + j * 8, lds + 12288 + s * 2048 + tid * 8);
      }
      __syncthreads();

      f32x4 s4[8];
#pragma unroll
      for (int n = 0; n < 8; ++n) s4[n] = (f32x4){0.f, 0.f, 0.f, 0.f};
#pragma unroll
      for (int kk = 0; kk < 2; ++kk) {
        bf16x8 aq = *(const bf16x8*)(lds + kk * 2048 + (w * 64 + lg * 16 + lr) * 8);
        __builtin_amdgcn_s_setprio(1);
#pragma unroll
        for (int jf = 0; jf < 8; ++jf) {
          bf16x8 bk = *(const bf16x8*)(lds + 4096 + kk * 4096 + (jf * 64 + lg * 16 + lr) * 8);
          s4[jf] = __builtin_amdgcn_mfma_f32_16x16x32_bf16(aq, bk, s4[jf], 0, 0, 0);
        }
        __builtin_amdgcn_s_setprio(0);
      }

      float pm[4];
#pragma unroll
      for (int r = 0; r < 4; ++r) pm[r] = -1e30f;
#pragma unroll
      for (int jf = 0; jf < 8; ++jf) {
        int gj = j0 + jf * 16 + lr;
#pragma unroll
        for (int r = 0; r < 4; ++r) {
          int gq = q0 + w * 16 + lg * 4 + r;
          float sv = s4[jf][r] * scale;
          if (gj > gq) sv = -1e30f;
          s4[jf][r] = sv;
          pm[r] = fmaxf(pm[r], sv);
        }
      }
#pragma unroll
      for (int r = 0; r < 4; ++r) {
#pragma unroll
        for (int m = 8; m >= 1; m >>= 1) pm[r] = fmaxf(pm[r], __shfl_xor(pm[r], m, 64));
      }
      float alpha[4];
#pragma unroll
      for (int r = 0; r < 4; ++r) {
        float mn = fmaxf(mrow[r], pm[r]);
        alpha[r] = expf(mrow[r] - mn);
        mrow[r] = mn;
      }
      float ps[4] = {0.f, 0.f, 0.f, 0.f};
#pragma unroll
      for (int jf = 0; jf < 8; ++jf) {
#pragma unroll
        for (int r = 0; r < 4; ++r) {
          float p = expf(s4[jf][r] - mrow[r]);
          s4[jf][r] = p;
          ps[r] += p;
        }
      }
#pragma unroll
      for (int r = 0; r < 4; ++r) {
#pragma unroll
        for (int m = 8; m >= 1; m >>= 1) ps[r] += __shfl_xor(ps[r], m, 64);
        lrow[r] = lrow[r] * alpha[r] + ps[r];
      }
#pragma unroll
      for (int n = 0; n < 4; ++n) {
#pragma unroll
        for (int r = 0; r < 4; ++r) accO[n][r] *= alpha[r];
      }

#pragma unroll
      for (int jf = 0; jf < 8; ++jf) {
        int s = jf >> 1;
        int rem = ((jf & 1) << 4) + lr;
        int base = s * 512 + (rem >> 3) * 128 + (rem & 7);
#pragma unroll
        for (int r = 0; r < 4; ++r) {
          int qloc = lg * 4 + r;
          Pw[base + qloc * 8] = (__bf16)s4[jf][r];
        }
      }
      asm volatile("s_waitcnt lgkmcnt(0)" ::: "memory");
      __builtin_amdgcn_sched_barrier(0);

#pragma unroll
      for (int s = 0; s < 4; ++s) {
        bf16x8 pa = *(const bf16x8*)(Pw + s * 512 + (lg * 16 + lr) * 8);
        __builtin_amdgcn_s_setprio(1);
#pragma unroll
        for (int nd = 0; nd < 4; ++nd) {
          bf16x8 bv = *(const bf16x8*)(lds + 12288 + s * 2048 + (nd * 64 + lg * 16 + lr) * 8);
          accO[nd] = __builtin_amdgcn_mfma_f32_16x16x32_bf16(pa, bv, accO[nd], 0, 0, 0);
        }
        __builtin_amdgcn_s_setprio(0);
      }
    }

#pragma unroll
    for (int nd = 0; nd < 4; ++nd) {
#pragma unroll
      for (int r = 0; r < 4; ++r) {
        int gq = q0 + w * 16 + lg * 4 + r;
        float val = accO[nd][r] / lrow[r];
        o[(size_t)(b * T_SEQ + gq) * D_MODEL + h * 64 + nd * 16 + lr] = (__bf16)val;
      }
    }
  }
}

// ---------------------------------------------------------------------------
extern "C" void kernel_launch(void* const* d_in, const int* in_sizes, int n_in,
                              void* d_out, int out_size, void* d_ws, size_t ws_size,
                              hipStream_t stream) {
  const int*   idx     = (const int*)d_in[0];
  const float* W_emb   = (const float*)d_in[1];
  const float* norm1_w = (const float*)d_in[2];
  const float* Wqkv    = (const float*)d_in[3];
  const float* Wout    = (const float*)d_in[4];
  const float* norm2_w = (const float*)d_in[5];
  const float* Wg      = (const float*)d_in[6];
  const float* Wu      = (const float*)d_in[7];
  const float* Wd      = (const float*)d_in[8];
  const float* fnorm   = (const float*)d_in[9];
  float* out = (float*)d_out;

  float*  x    = (float*)d_ws;                              // 2048*1024 f32
  float*  tab  = x + (size_t)NTOK * D_MODEL;                // 2*32768 f32
  __bf16* hb   = (__bf16*)(tab + 2 * 32768);                // 2048*1024
  __bf16* ob   = hb + (size_t)NTOK * D_MODEL;               // 2048*1024
  __bf16* ga   = ob + (size_t)NTOK * D_MODEL;               // 2048*2816
  __bf16* Qrb  = ga + (size_t)NTOK * HID_PAD;               // 32*1024*64
  __bf16* Krb  = Qrb + (size_t)32 * T_SEQ * 64;
  __bf16* Vtb  = Krb + (size_t)32 * T_SEQ * 64;
  __bf16* wbuf = Vtb + (size_t)32 * T_SEQ * 64;

  __bf16* wqkvT = wbuf;                                     // [3072][1024]
  __bf16* woutT = wqkvT + (size_t)3 * D_MODEL * D_MODEL;    // [1024][1024]
  __bf16* wguT  = woutT + (size_t)D_MODEL * D_MODEL;        // [5632][1024]
  __bf16* wdT   = wguT + (size_t)2 * HID_PAD * D_MODEL;     // [1024][2816]

  embed_kernel<<<NTOK, 256, 0, stream>>>(idx, W_emb, x);
  rope_table_kernel<<<128, 256, 0, stream>>>(tab);

  for (int l = 0; l < NLAYER; ++l) {
    tp5_kernel<<<3136, 256, 0, stream>>>(
        Wqkv + (size_t)l * D_MODEL * 3 * D_MODEL,
        Wout + (size_t)l * D_MODEL * D_MODEL,
        Wg + (size_t)l * D_MODEL * HID,
        Wu + (size_t)l * D_MODEL * HID,
        Wd + (size_t)l * HID * D_MODEL,
        wqkvT, woutT, wguT, wdT);

    rmsnorm_kernel<<<NTOK, 256, 0, stream>>>(x, norm1_w + (size_t)l * D_MODEL, hb);
    gemm8<128, 256, 2, 4, 5><<<dim3(16, 12), 512, 0, stream>>>(
        hb, wqkvT, nullptr, nullptr, D_MODEL, 3 * D_MODEL, tab, Qrb, Krb, Vtb);
    attn_kernel<<<dim3(8, 32), 256, 0, stream>>>(Qrb, Krb, Vtb, ob);
    gemm8<128, 64, 4, 1, 1><<<dim3(16, 16), 256, 0, stream>>>(
        ob, woutT, x, x, D_MODEL, D_MODEL, nullptr, nullptr, nullptr, nullptr);
    rmsnorm_kernel<<<NTOK, 256, 0, stream>>>(x, norm2_w + (size_t)l * D_MODEL, hb);
    gemm8<128, 256, 2, 4, 4><<<dim3(16, 22), 512, 0, stream>>>(
        hb, wguT, nullptr, ga, D_MODEL, HID_PAD, nullptr, nullptr, nullptr, nullptr);
    gemm8<128, 64, 4, 1, 1><<<dim3(16, 16), 256, 0, stream>>>(
        ga, wdT, x, x, HID_PAD, D_MODEL, nullptr, nullptr, nullptr, nullptr);
  }

  rmsnorm_kernel<<<NTOK, 256, 0, stream>>>(x, fnorm, hb);
  convert_bf16_kernel<<<2048, 256, 0, stream>>>(W_emb, wbuf, VOCAB * D_MODEL / 4);
  gemm8<256, 256, 2, 4, 0><<<dim3(8, 125), 512, 0, stream>>>(
      hb, wbuf, nullptr, out, D_MODEL, VOCAB, nullptr, nullptr, nullptr, nullptr);
}